// Round 25
// baseline (39.028 us; speedup 1.0000x reference)
//
#include <hip/hip_runtime.h>

// ConvTranspose4d via bf16 MFMA (R25 = R24 + global_load_lds staging, linear LDS).
// Gather: out[co,f,od,oh,ow] = sum_{ci,i,kd,kh,kw} x[ci,f+i,id,ih,iw]*W[ci,co,i,kd,kh,kw]
// Stack: R16 E/O fold; R17 LDS staging; R19 od-pair; R21 addressing; R23/R24 f-triple
//   (32.9us best). R18 packed / R22 transposed layouts both measured NEUTRAL -> revert
//   to linear [row][48] f32 rows, which is global_load_lds-compatible:
// R25: staging = 45 x global_load_lds(width16) per block (240 rows x 192B = 45x1024B;
//   dest wave-uniform base + lane*16, per-LANE global src carries the row-decode
//   clamps). Replaces ~100 instr/thread (loads+perms+ds_writes+temps) with async DMA.
//   Compute rebuilds dE per quarter: 2x ds_read_b32 (read2-fused) + v_perm (R18 proved
//   this costs ~0.5us). Row stride 48 = 16 mod 32 banks -> 2-way alias = free (m136).
//   n=47 pair reads next row's x[0]: finite x 0-weight -> exact; last row overruns into
//   lds[11520], zeroed by one thread (NaN x 0 guard). Kept outputs bit-identical ->
//   absmax must stay EXACTLY 0.0078125 (gate).

typedef float  f32x4  __attribute__((ext_vector_type(4)));
typedef short  bf16x8 __attribute__((ext_vector_type(8)));
typedef unsigned int u32;
typedef u32    u32x4  __attribute__((ext_vector_type(4)));

namespace {
constexpr int T_ = 8, D_ = 24, H_ = 48, W_ = 48;
constexpr int TO = 6, DO_ = 47, HO = 95, WO = 95;
constexpr int XCS = T_ * D_ * H_ * W_;
constexpr int XFS = D_ * H_ * W_;
constexpr int XDS = H_ * W_;
constexpr long OCS = (long)TO * DO_ * HO * WO;
constexpr int OFS = DO_ * HO * WO;
constexpr int ODS = HO * WO;

constexpr int AG[4] = {24, 12, 12, 8};
constexpr int AOFF[4] = {0, 3072, 4608, 6144};         // shorts; total 7168 = 14 KB

__global__ __launch_bounds__(256) void pack_kernel(const float* __restrict__ w,
                                                   unsigned short* __restrict__ A) {
  const int tid = blockIdx.x * 256 + threadIdx.x;
  const int nthr = gridDim.x * 256;
  const int KR[4] = {192, 96, 96, 48};
  for (int c = 0; c < 4; ++c) {
    const int cnt = AG[c] * 128;                       // [g][r(16)][j(8)] shorts
    for (int e = tid; e < cnt; e += nthr) {
      const int j = e & 7, r = (e >> 3) & 15, g = e >> 7;
      const int k = g * 8 + j;
      float v = 0.f;
      if (k < KR[c]) {
        int gg = -1, kd = 1, kh = 1;
        const int cc = j & 1;
        if (c == 0)      { gg = g;               kd = ((j >> 1) & 1) ? 2 : 0; kh = ((j >> 2) & 1) ? 0 : 2; }
        else if (c == 1) { gg = 2 * g + (j >> 2); kd = ((j >> 1) & 1) ? 2 : 0; kh = 1; }
        else if (c == 2) { gg = 2 * g + (j >> 2); kd = 1; kh = ((j >> 1) & 1) ? 0 : 2; }
        else             { gg = 4 * g + (j >> 1); kd = 1; kh = 1; }
        if (gg >= 0 && gg < 24) {
          const int ci = gg / 3, i = gg - 3 * (gg / 3);
          const int co = r & 7;
          int kw = (r < 8) ? (cc == 0 ? 1 : -1) : (cc == 0 ? 2 : 0);
          if (kw >= 0) v = w[ci * 648 + co * 81 + i * 27 + kd * 9 + kh * 3 + kw];
        }
      }
      u32 u = __float_as_uint(v);
      u += 0x7FFFu + ((u >> 16) & 1u);                 // RNE to bf16
      A[AOFF[c] + e] = (unsigned short)(u >> 16);
    }
  }
}

// row group base for (gg = ci*3+i, dl = f-offset 0..2): gg' = ci*5 + i + dl; 6 rows/gg'
__device__ __forceinline__ int rowb(int gg, int dl) {
  const int ci = gg / 3;
  return (ci * 5 + (gg - 3 * ci) + dl) * 6;
}

template<int PD, int PH>
__device__ __forceinline__ void wave_body(
    const u32* __restrict__ lds, const unsigned short* __restrict__ A,
    float* __restrict__ out, int f0, int od, int oh, int ihb, int lane)
{
  constexpr int CLS = (PD && PH) ? 0 : PD ? 1 : PH ? 2 : 3;
  constexpr int NSTEP = (CLS == 0) ? 6 : (CLS == 3) ? 2 : 3;
  const int c15 = lane & 15, q = lane >> 4;
  const int th = ((oh + PH) >> 1) - ihb;               // top h-row (0..2)

  bf16x8 af[NSTEP];
  {
    const unsigned short* Ap = A + AOFF[CLS] + c15 * 8;
    #pragma unroll
    for (int s = 0; s < NSTEP; ++s)
      af[s] = *reinterpret_cast<const bf16x8*>(Ap + (s * 4 + q) * 128);
  }

  f32x4 acc[3][3];                                     // [dl][blk]
  #pragma unroll
  for (int dl = 0; dl < 3; ++dl)
    #pragma unroll
    for (int b = 0; b < 3; ++b) acc[dl][b] = {0, 0, 0, 0};

  #pragma unroll
  for (int blk = 0; blk < 3; ++blk) {
    const int n = blk * 16 + c15;
    // dE word for (row, n): lo16 = bf16-trunc x[n], hi16 = bf16-trunc x[n+1]
    auto RD = [&](int row) -> u32 {
      const u32* r = lds + row * 48 + n;
      return __builtin_amdgcn_perm(r[1], r[0], 0x07060302u);
    };
    #pragma unroll
    for (int s = 0; s < NSTEP; ++s) {
      const int G = s * 4 + q;
      #pragma unroll
      for (int dl = 0; dl < 3; ++dl) {
        u32x4 ue;
        if constexpr (CLS == 0) {                      // rows rowb + {2th-2..2th+1}
          const int b = rowb(G, dl) + 2 * th - 2;
          ue = u32x4{RD(b), RD(b + 1), RD(b + 2), RD(b + 3)};
        } else if constexpr (CLS == 1) {               // (g0,e0),(g0,e1),(g1,e0),(g1,e1)
          const int b0 = rowb(2 * G, dl) + 2 * th;
          const int b1 = rowb(2 * G + 1, dl) + 2 * th;
          ue = u32x4{RD(b0), RD(b0 + 1), RD(b1), RD(b1 + 1)};
        } else if constexpr (CLS == 2) {               // (g,th-1),(g,th) e=1 pairs
          const int r0 = rowb(2 * G, dl), r1 = rowb(2 * G + 1, dl);
          ue = u32x4{RD(r0 + 2 * th - 1), RD(r0 + 2 * th + 1),
                     RD(r1 + 2 * th - 1), RD(r1 + 2 * th + 1)};
        } else {                                       // g ascending, e=1, t=th
          #pragma unroll
          for (int d = 0; d < 4; ++d) {
            int gg = 4 * G + d; gg = (gg > 23) ? 23 : gg;  // k>=48 -> A==0, row dontcare
            ue[d] = RD(rowb(gg, dl) + 2 * th + 1);
          }
        }
        acc[dl][blk] = __builtin_amdgcn_mfma_f32_16x16x32_bf16(af[s], __builtin_bit_cast(bf16x8, ue), acc[dl][blk], 0, 0, 0);
      }
    }
  }

  // D rows 0-7 = co (even ow), 8-15 = co (odd ow); row = q*4+j, col = c15.
  const int isO = (q >= 2);
  const int co0 = (q & 1) * 4;
  #pragma unroll
  for (int dl = 0; dl < 3; ++dl) {
    #pragma unroll
    for (int blk = 0; blk < 3; ++blk) {
      const int ow = blk * 32 + 2 * c15 + isO;
      if (ow < 95) {
        const long ob = (long)(f0 + dl) * OFS + (long)od * ODS + (long)oh * HO + ow;
        #pragma unroll
        for (int j = 0; j < 4; ++j)
          out[(long)(co0 + j) * OCS + ob] = acc[dl][blk][j];
      }
    }
  }
}

constexpr int NBLK = 2 * 24 * 24;                      // f-triple x od-pair x og = 1152

__global__ __launch_bounds__(512) void convt4d_kernel(
    const float* __restrict__ x, const unsigned short* __restrict__ A,
    float* __restrict__ out)
{
  __shared__ u32 lds[240 * 48 + 16];                   // 46144 B; [row][48] f32 bits

  constexpr int qq = NBLK / 8;                         // 144 (NBLK%8==0)
  const int bid = blockIdx.x;
  const int L = (bid & 7) * qq + (bid >> 3);           // bijective XCD swizzle
  const int og = L % 24;
  const int rest = L / 24;
  const int odp = rest % 24, fp = rest / 24;           // od pair {2odp,2odp+1}; f-triple
  const int f0 = 3 * fp;                               // f0 in {0,3}; frames f0..f0+4

  const int tid = threadIdx.x;
  const int ihb = og * 2;
  const int idp = odp + 1;                             // e=0 plane = p+1, e=1 plane = p

  // R25 staging: 45 async DMA chunks of 1024B. Chunk k covers float idx k*256..k*256+255
  // of the linear union; lane ln carries 16B at fidx = k*256 + ln*4 with per-lane src:
  //   row = fidx/48 = (ci*5+fi)*6 + t*2 + e ; src = x[ci, f0+fi, plane(e), ih(t), off]
  {
    const int wv = tid >> 6, ln = tid & 63;
    for (int k = wv; k < 45; k += 8) {                 // k wave-uniform
      const int fidx = k * 256 + ln * 4;
      const int row = fidx / 48;
      const int off = fidx - row * 48;
      const int rem = row % 6;
      const int t = rem >> 1, e = rem & 1;
      const int ggp = row / 6;
      const int ci = ggp / 5, fi = ggp - 5 * ci;
      int plane = idp - e; if (plane > 23) plane = 23; // odp=23,e=0: unused, clamp OOB
      int ih = ihb + t; if (ih > 47) ih = 47;          // og=23 t=2: unused, clamp
      const float* src = x + ci * XCS + (f0 + fi) * XFS + plane * XDS + ih * W_ + off;
      __builtin_amdgcn_global_load_lds(
          (const __attribute__((address_space(1))) u32*)src,
          ((__attribute__((address_space(3))) u32*)lds) + k * 256,
          16, 0, 0);
    }
    if (tid == 0) lds[240 * 48] = 0;                   // last row's x[48]-slot: finite guard
  }
  __syncthreads();

  const int w = tid >> 6, lane = tid & 63;
  const int half = w >> 2;                             // 0: od=2p (pd0), 1: od=2p+1 (pd1)
  const int od = 2 * odp + half;
  if (od > 46) return;                                 // odp=23 pd1 half: no od=47
  int oh = og * 4 + (w & 3);
  if (oh > 94) oh = 93;                                // og=23,w&3=3: dup of w&3=1 (benign)
  if (half) {
    if (oh & 1) wave_body<1, 1>(lds, A, out, f0, od, oh, ihb, lane);
    else        wave_body<1, 0>(lds, A, out, f0, od, oh, ihb, lane);
  } else {
    if (oh & 1) wave_body<0, 1>(lds, A, out, f0, od, oh, ihb, lane);
    else        wave_body<0, 0>(lds, A, out, f0, od, oh, ihb, lane);
  }
}
}  // namespace

extern "C" void kernel_launch(void* const* d_in, const int* in_sizes, int n_in,
                              void* d_out, int out_size, void* d_ws, size_t ws_size,
                              hipStream_t stream) {
  const float* x = (const float*)d_in[0];
  const float* w = (const float*)d_in[1];
  float* out = (float*)d_out;
  unsigned short* A = (unsigned short*)d_ws;           // 7168 shorts = 14 KB
  hipLaunchKernelGGL(pack_kernel, dim3(8), dim3(256), 0, stream, w, A);
  hipLaunchKernelGGL(convt4d_kernel, dim3(NBLK), dim3(512), 0, stream, x, A, out);
}

// Round 26
// 35.696 us; speedup vs baseline: 1.0933x; 1.0933x over previous
//
#include <hip/hip_runtime.h>

// ConvTranspose4d via bf16 MFMA (R26 = R24 tiling + row-major LDS + per-ROW staging).
// Gather: out[co,f,od,oh,ow] = sum_{ci,i,kd,kh,kw} x[ci,f+i,id,ih,iw]*W[ci,co,i,kd,kh,kw]
// Stack: R16 E/O fold; R17 LDS staging; R19 od-pair; R21 addressing; R23/R24 f-triple
//   (32.9us best). R25 (gload_lds DMA) REVERTED: scattered-row chunks serialize TA and
//   forced un-packed compute reads (+6us).
// R26a: row-major packed LDS lds[row*48+w] (R21 layout, compute-neutral vs transposed
//   per R22) -> staging writes are b128 (R24 transpose cost 4x b32 scattered writes).
//   Compute quads: rows 48 dwords apart -> ds_read2_b32 fusable.
// R26b: per-ROW staging (1 thread = 48-float row): 12 back-to-back dwordx4, boundary
//   word from v[ch+1].x in-reg -> VMEM instr 5760->2880/block, zero scalar extras.
//   240/512 threads active in stage; latency covered by co-resident blocks.
// Packing bit-identical (word47 hi=0) -> absmax must stay EXACTLY 0.0078125 (gate).

typedef float  f32x4  __attribute__((ext_vector_type(4)));
typedef float  f4a    __attribute__((ext_vector_type(4)));
typedef short  bf16x8 __attribute__((ext_vector_type(8)));
typedef unsigned int u32;
typedef u32    u32x4  __attribute__((ext_vector_type(4)));

namespace {
constexpr int T_ = 8, D_ = 24, H_ = 48, W_ = 48;
constexpr int TO = 6, DO_ = 47, HO = 95, WO = 95;
constexpr int XCS = T_ * D_ * H_ * W_;
constexpr int XFS = D_ * H_ * W_;
constexpr int XDS = H_ * W_;
constexpr long OCS = (long)TO * DO_ * HO * WO;
constexpr int OFS = DO_ * HO * WO;
constexpr int ODS = HO * WO;

constexpr int AG[4] = {24, 12, 12, 8};
constexpr int AOFF[4] = {0, 3072, 4608, 6144};         // shorts; total 7168 = 14 KB

__global__ __launch_bounds__(256) void pack_kernel(const float* __restrict__ w,
                                                   unsigned short* __restrict__ A) {
  const int tid = blockIdx.x * 256 + threadIdx.x;
  const int nthr = gridDim.x * 256;
  const int KR[4] = {192, 96, 96, 48};
  for (int c = 0; c < 4; ++c) {
    const int cnt = AG[c] * 128;                       // [g][r(16)][j(8)] shorts
    for (int e = tid; e < cnt; e += nthr) {
      const int j = e & 7, r = (e >> 3) & 15, g = e >> 7;
      const int k = g * 8 + j;
      float v = 0.f;
      if (k < KR[c]) {
        int gg = -1, kd = 1, kh = 1;
        const int cc = j & 1;
        if (c == 0)      { gg = g;               kd = ((j >> 1) & 1) ? 2 : 0; kh = ((j >> 2) & 1) ? 0 : 2; }
        else if (c == 1) { gg = 2 * g + (j >> 2); kd = ((j >> 1) & 1) ? 2 : 0; kh = 1; }
        else if (c == 2) { gg = 2 * g + (j >> 2); kd = 1; kh = ((j >> 1) & 1) ? 0 : 2; }
        else             { gg = 4 * g + (j >> 1); kd = 1; kh = 1; }
        if (gg >= 0 && gg < 24) {
          const int ci = gg / 3, i = gg - 3 * (gg / 3);
          const int co = r & 7;
          int kw = (r < 8) ? (cc == 0 ? 1 : -1) : (cc == 0 ? 2 : 0);
          if (kw >= 0) v = w[ci * 648 + co * 81 + i * 27 + kd * 9 + kh * 3 + kw];
        }
      }
      u32 u = __float_as_uint(v);
      u += 0x7FFFu + ((u >> 16) & 1u);                 // RNE to bf16
      A[AOFF[c] + e] = (unsigned short)(u >> 16);
    }
  }
}

// row group base for (gg = ci*3+i, dl = f-offset 0..2): gg' = ci*5 + i + dl; 6 rows/gg'
__device__ __forceinline__ int rowb(int gg, int dl) {
  const int ci = gg / 3;
  return (ci * 5 + (gg - 3 * ci) + dl) * 6;
}

template<int PD, int PH>
__device__ __forceinline__ void wave_body(
    const u32* __restrict__ lds, const unsigned short* __restrict__ A,
    float* __restrict__ out, int f0, int od, int oh, int ihb, int lane)
{
  constexpr int CLS = (PD && PH) ? 0 : PD ? 1 : PH ? 2 : 3;
  constexpr int NSTEP = (CLS == 0) ? 6 : (CLS == 3) ? 2 : 3;
  const int c15 = lane & 15, q = lane >> 4;
  const int th = ((oh + PH) >> 1) - ihb;               // top h-row (0..2)

  bf16x8 af[NSTEP];
  {
    const unsigned short* Ap = A + AOFF[CLS] + c15 * 8;
    #pragma unroll
    for (int s = 0; s < NSTEP; ++s)
      af[s] = *reinterpret_cast<const bf16x8*>(Ap + (s * 4 + q) * 128);
  }

  f32x4 acc[3][3];                                     // [dl][blk]
  #pragma unroll
  for (int dl = 0; dl < 3; ++dl)
    #pragma unroll
    for (int b = 0; b < 3; ++b) acc[dl][b] = {0, 0, 0, 0};

  #pragma unroll
  for (int blk = 0; blk < 3; ++blk) {
    const int n = blk * 16 + c15;
    const u32* col = lds + n;                          // word n of each row
    #pragma unroll
    for (int s = 0; s < NSTEP; ++s) {
      const int G = s * 4 + q;
      #pragma unroll
      for (int dl = 0; dl < 3; ++dl) {
        u32x4 ue;
        if constexpr (CLS == 0) {                      // rows rowb + {2th-2..2th+1}
          const int b = rowb(G, dl) + 2 * th - 2;
          ue = u32x4{col[b * 48], col[(b + 1) * 48], col[(b + 2) * 48], col[(b + 3) * 48]};
        } else if constexpr (CLS == 1) {               // (g0,e0),(g0,e1),(g1,e0),(g1,e1)
          const int b0 = rowb(2 * G, dl) + 2 * th;
          const int b1 = rowb(2 * G + 1, dl) + 2 * th;
          ue = u32x4{col[b0 * 48], col[(b0 + 1) * 48], col[b1 * 48], col[(b1 + 1) * 48]};
        } else if constexpr (CLS == 2) {               // (g,th-1),(g,th) e=1 pairs
          const int r0 = rowb(2 * G, dl), r1 = rowb(2 * G + 1, dl);
          ue = u32x4{col[(r0 + 2 * th - 1) * 48], col[(r0 + 2 * th + 1) * 48],
                     col[(r1 + 2 * th - 1) * 48], col[(r1 + 2 * th + 1) * 48]};
        } else {                                       // g ascending, e=1, t=th
          #pragma unroll
          for (int d = 0; d < 4; ++d) {
            int gg = 4 * G + d; gg = (gg > 23) ? 23 : gg;  // k>=48 -> A==0, row dontcare
            ue[d] = col[(rowb(gg, dl) + 2 * th + 1) * 48];
          }
        }
        acc[dl][blk] = __builtin_amdgcn_mfma_f32_16x16x32_bf16(af[s], __builtin_bit_cast(bf16x8, ue), acc[dl][blk], 0, 0, 0);
      }
    }
  }

  // D rows 0-7 = co (even ow), 8-15 = co (odd ow); row = q*4+j, col = c15.
  const int isO = (q >= 2);
  const int co0 = (q & 1) * 4;
  #pragma unroll
  for (int dl = 0; dl < 3; ++dl) {
    #pragma unroll
    for (int blk = 0; blk < 3; ++blk) {
      const int ow = blk * 32 + 2 * c15 + isO;
      if (ow < 95) {
        const long ob = (long)(f0 + dl) * OFS + (long)od * ODS + (long)oh * HO + ow;
        #pragma unroll
        for (int j = 0; j < 4; ++j)
          out[(long)(co0 + j) * OCS + ob] = acc[dl][blk][j];
      }
    }
  }
}

constexpr int NBLK = 2 * 24 * 24;                      // f-triple x od-pair x og = 1152

__global__ __launch_bounds__(512) void convt4d_kernel(
    const float* __restrict__ x, const unsigned short* __restrict__ A,
    float* __restrict__ out)
{
  __shared__ u32 lds[240 * 48];                        // 46080 B; [row][48] packed words

  constexpr int qq = NBLK / 8;                         // 144 (NBLK%8==0)
  const int bid = blockIdx.x;
  const int L = (bid & 7) * qq + (bid >> 3);           // bijective XCD swizzle
  const int og = L % 24;
  const int rest = L / 24;
  const int odp = rest % 24, fp = rest / 24;           // od pair {2odp,2odp+1}; f-triple
  const int f0 = 3 * fp;                               // f0 in {0,3}; frames f0..f0+4

  const int tid = threadIdx.x;
  const int ihb = og * 2;
  const int idp = odp + 1;                             // e=0 plane = p+1, e=1 plane = p

  // R26 staging: one thread per 48-float row. 12 back-to-back dwordx4 loads, pack 48
  // words in-register (word w = bf(x[w]) | bf(x[w+1])<<16, x[48]=0), 12 b128 ds_writes.
  for (int row = tid; row < 240; row += 512) {
    const int rem = row % 6;
    const int t = rem >> 1, e = rem & 1;
    const int ggp = row / 6;
    const int ci = ggp / 5, fi = ggp - 5 * ci;
    int plane = idp - e; if (plane > 23) plane = 23;   // odp=23,e=0: unused, clamp OOB
    int ih = ihb + t; if (ih > 47) ih = 47;            // og=23 t=2: unused, clamp
    const float* src = x + ci * XCS + (f0 + fi) * XFS + plane * XDS + ih * W_;
    f32x4 v[12];
    #pragma unroll
    for (int ch = 0; ch < 12; ++ch)
      v[ch] = *reinterpret_cast<const f4a*>(src + ch * 4);
    u32* dst = lds + row * 48;
    #pragma unroll
    for (int ch = 0; ch < 12; ++ch) {
      const u32 b0 = __float_as_uint(v[ch].x), b1 = __float_as_uint(v[ch].y);
      const u32 b2 = __float_as_uint(v[ch].z), b3 = __float_as_uint(v[ch].w);
      const u32 b4 = (ch == 11) ? 0u : __float_as_uint(v[ch + 1].x);
      const u32x4 pk = {__builtin_amdgcn_perm(b1, b0, 0x07060302u),
                        __builtin_amdgcn_perm(b2, b1, 0x07060302u),
                        __builtin_amdgcn_perm(b3, b2, 0x07060302u),
                        __builtin_amdgcn_perm(b4, b3, 0x07060302u)};
      *reinterpret_cast<u32x4*>(dst + ch * 4) = pk;    // 16B-aligned
    }
  }
  __syncthreads();

  const int w = tid >> 6, lane = tid & 63;
  const int half = w >> 2;                             // 0: od=2p (pd0), 1: od=2p+1 (pd1)
  const int od = 2 * odp + half;
  if (od > 46) return;                                 // odp=23 pd1 half: no od=47
  int oh = og * 4 + (w & 3);
  if (oh > 94) oh = 93;                                // og=23,w&3=3: dup of w&3=1 (benign)
  if (half) {
    if (oh & 1) wave_body<1, 1>(lds, A, out, f0, od, oh, ihb, lane);
    else        wave_body<1, 0>(lds, A, out, f0, od, oh, ihb, lane);
  } else {
    if (oh & 1) wave_body<0, 1>(lds, A, out, f0, od, oh, ihb, lane);
    else        wave_body<0, 0>(lds, A, out, f0, od, oh, ihb, lane);
  }
}
}  // namespace

extern "C" void kernel_launch(void* const* d_in, const int* in_sizes, int n_in,
                              void* d_out, int out_size, void* d_ws, size_t ws_size,
                              hipStream_t stream) {
  const float* x = (const float*)d_in[0];
  const float* w = (const float*)d_in[1];
  float* out = (float*)d_out;
  unsigned short* A = (unsigned short*)d_ws;           // 7168 shorts = 14 KB
  hipLaunchKernelGGL(pack_kernel, dim3(8), dim3(256), 0, stream, w, A);
  hipLaunchKernelGGL(convt4d_kernel, dim3(NBLK), dim3(512), 0, stream, x, A, out);
}

// Round 27
// 31.742 us; speedup vs baseline: 1.2295x; 1.1246x over previous
//
#include <hip/hip_runtime.h>

// ConvTranspose4d via bf16 MFMA (R27 = R24 with dl-OUTER compute loop: acc 36->12 VGPR).
// Gather: out[co,f,od,oh,ow] = sum_{ci,i,kd,kh,kw} x[ci,f+i,id,ih,iw]*W[ci,co,i,kd,kh,kw]
// Stack: R16 E/O fold; R17 LDS staging; R19 od-pair; R21 addressing; R22 transposed
//   [n][row] LDS (load-bearing: R26's row-major revert cost 2.8us); R23/R24 f-triple.
// R27: LDS reads are per-(blk,s,dl) regardless of loop order -> hoist dl OUTERMOST,
//   keep only acc[3] (12 VGPR, was 36), store each frame before the next. Zero change
//   to traffic or math order; only live-register shrink. Theory: R24 is residency-
//   limited (issue accounting: ~33K of 79K cyc/CU used, nothing saturated; VGPR~105 ->
//   4 waves/SIMD -> 2 blocks/CU). -24 VGPR -> 6 waves/SIMD -> 3 blocks/CU (+50%).
//   R25/R26 staging restructures REVERTED (both regressed; stage already hidden).
//   Per-output accumulation sequence identical -> absmax EXACTLY 0.0078125 (gate).

typedef float  f32x4  __attribute__((ext_vector_type(4)));
typedef float  f4a    __attribute__((ext_vector_type(4)));
typedef short  bf16x8 __attribute__((ext_vector_type(8)));
typedef unsigned int u32;
typedef u32    u32x2  __attribute__((ext_vector_type(2)));
typedef u32    u32x4  __attribute__((ext_vector_type(4)));

namespace {
constexpr int T_ = 8, D_ = 24, H_ = 48, W_ = 48;
constexpr int TO = 6, DO_ = 47, HO = 95, WO = 95;
constexpr int XCS = T_ * D_ * H_ * W_;
constexpr int XFS = D_ * H_ * W_;
constexpr int XDS = H_ * W_;
constexpr long OCS = (long)TO * DO_ * HO * WO;
constexpr int OFS = DO_ * HO * WO;
constexpr int ODS = HO * WO;

constexpr int AG[4] = {24, 12, 12, 8};
constexpr int AOFF[4] = {0, 3072, 4608, 6144};         // shorts; total 7168 = 14 KB
constexpr int NRSTR = 242;                             // per-column row stride (u32)

__global__ __launch_bounds__(256) void pack_kernel(const float* __restrict__ w,
                                                   unsigned short* __restrict__ A) {
  const int tid = blockIdx.x * 256 + threadIdx.x;
  const int nthr = gridDim.x * 256;
  const int KR[4] = {192, 96, 96, 48};
  for (int c = 0; c < 4; ++c) {
    const int cnt = AG[c] * 128;                       // [g][r(16)][j(8)] shorts
    for (int e = tid; e < cnt; e += nthr) {
      const int j = e & 7, r = (e >> 3) & 15, g = e >> 7;
      const int k = g * 8 + j;
      float v = 0.f;
      if (k < KR[c]) {
        int gg = -1, kd = 1, kh = 1;
        const int cc = j & 1;
        if (c == 0)      { gg = g;               kd = ((j >> 1) & 1) ? 2 : 0; kh = ((j >> 2) & 1) ? 0 : 2; }
        else if (c == 1) { gg = 2 * g + (j >> 2); kd = ((j >> 1) & 1) ? 2 : 0; kh = 1; }
        else if (c == 2) { gg = 2 * g + (j >> 2); kd = 1; kh = ((j >> 1) & 1) ? 0 : 2; }
        else             { gg = 4 * g + (j >> 1); kd = 1; kh = 1; }
        if (gg >= 0 && gg < 24) {
          const int ci = gg / 3, i = gg - 3 * (gg / 3);
          const int co = r & 7;
          int kw = (r < 8) ? (cc == 0 ? 1 : -1) : (cc == 0 ? 2 : 0);
          if (kw >= 0) v = w[ci * 648 + co * 81 + i * 27 + kd * 9 + kh * 3 + kw];
        }
      }
      u32 u = __float_as_uint(v);
      u += 0x7FFFu + ((u >> 16) & 1u);                 // RNE to bf16
      A[AOFF[c] + e] = (unsigned short)(u >> 16);
    }
  }
}

// row group base for (gg = ci*3+i, dl = f-offset 0..2): gg' = ci*5 + i + dl; 6 rows/gg'
__device__ __forceinline__ int rowb(int gg, int dl) {
  const int ci = gg / 3;
  return (ci * 5 + (gg - 3 * ci) + dl) * 6;
}

template<int PD, int PH>
__device__ __forceinline__ void wave_body(
    const u32* __restrict__ lds, const unsigned short* __restrict__ A,
    float* __restrict__ out, int f0, int od, int oh, int ihb, int lane)
{
  constexpr int CLS = (PD && PH) ? 0 : PD ? 1 : PH ? 2 : 3;
  constexpr int NSTEP = (CLS == 0) ? 6 : (CLS == 3) ? 2 : 3;
  const int c15 = lane & 15, q = lane >> 4;
  const int th = ((oh + PH) >> 1) - ihb;               // top h-row (0..2)

  bf16x8 af[NSTEP];
  {
    const unsigned short* Ap = A + AOFF[CLS] + c15 * 8;
    #pragma unroll
    for (int s = 0; s < NSTEP; ++s)
      af[s] = *reinterpret_cast<const bf16x8*>(Ap + (s * 4 + q) * 128);
  }

  const int isO = (q >= 2);
  const int co0 = (q & 1) * 4;

  #pragma unroll
  for (int dl = 0; dl < 3; ++dl) {                     // dl OUTER (R27): acc[3] only
    f32x4 acc[3];
    #pragma unroll
    for (int b = 0; b < 3; ++b) acc[b] = {0, 0, 0, 0};

    #pragma unroll
    for (int blk = 0; blk < 3; ++blk) {
      const int n = blk * 16 + c15;
      const u32* col = lds + n * NRSTR;
      #pragma unroll
      for (int s = 0; s < NSTEP; ++s) {
        const int G = s * 4 + q;
        u32x4 ue;
        if constexpr (CLS == 0) {                      // rows rowb + {2th-2..2th+1}
          const u32* b = col + rowb(G, dl) + 2 * th - 2;
          const u32x2 lo = *reinterpret_cast<const u32x2*>(b);
          const u32x2 hi = *reinterpret_cast<const u32x2*>(b + 2);
          ue = u32x4{lo.x, lo.y, hi.x, hi.y};
        } else if constexpr (CLS == 1) {               // (g0,e0),(g0,e1),(g1,e0),(g1,e1)
          const u32* b0 = col + rowb(2 * G, dl) + 2 * th;
          const u32* b1 = col + rowb(2 * G + 1, dl) + 2 * th;
          const u32x2 lo = *reinterpret_cast<const u32x2*>(b0);
          const u32x2 hi = *reinterpret_cast<const u32x2*>(b1);
          ue = u32x4{lo.x, lo.y, hi.x, hi.y};
        } else if constexpr (CLS == 2) {               // (g,th-1),(g,th) e=1 pairs
          const int r0 = rowb(2 * G, dl), r1 = rowb(2 * G + 1, dl);
          ue = u32x4{col[r0 + 2 * th - 1], col[r0 + 2 * th + 1],
                     col[r1 + 2 * th - 1], col[r1 + 2 * th + 1]};
        } else {                                       // g ascending, e=1, t=th
          #pragma unroll
          for (int d = 0; d < 4; ++d) {
            int gg = 4 * G + d; gg = (gg > 23) ? 23 : gg;  // k>=48 -> A==0, row dontcare
            ue[d] = col[rowb(gg, dl) + 2 * th + 1];
          }
        }
        acc[blk] = __builtin_amdgcn_mfma_f32_16x16x32_bf16(af[s], __builtin_bit_cast(bf16x8, ue), acc[blk], 0, 0, 0);
      }
    }

    // store frame f0+dl: D rows 0-7 = co (even ow), 8-15 = co (odd ow)
    #pragma unroll
    for (int blk = 0; blk < 3; ++blk) {
      const int ow = blk * 32 + 2 * c15 + isO;
      if (ow < 95) {
        const long ob = (long)(f0 + dl) * OFS + (long)od * ODS + (long)oh * HO + ow;
        #pragma unroll
        for (int j = 0; j < 4; ++j)
          out[(long)(co0 + j) * OCS + ob] = acc[blk][j];
      }
    }
  }
}

constexpr int NBLK = 2 * 24 * 24;                      // f-triple x od-pair x og = 1152

__global__ __launch_bounds__(512) void convt4d_kernel(
    const float* __restrict__ x, const unsigned short* __restrict__ A,
    float* __restrict__ out)
{
  __shared__ u32 lds[48 * NRSTR];                      // 46464 B

  constexpr int qq = NBLK / 8;                         // 144 (NBLK%8==0)
  const int bid = blockIdx.x;
  const int L = (bid & 7) * qq + (bid >> 3);           // bijective XCD swizzle
  const int og = L % 24;
  const int rest = L / 24;
  const int odp = rest % 24, fp = rest / 24;           // od pair {2odp,2odp+1}; f-triple
  const int f0 = 3 * fp;                               // f0 in {0,3}; frames f0..f0+4

  const int tid = threadIdx.x;
  const int ihb = og * 2;
  const int idp = odp + 1;                             // e=0 plane = p+1, e=1 plane = p

  // stage 240-row union PRE-PACKED + TRANSPOSED: lds[n*NRSTR + row] =
  //   bf(x[n]) | bf(x[n+1])<<16 ; row = (ci*5 + fi)*6 + t*2 + e, fi = frame - f0 (0..4)
  for (int c = tid; c < 240 * 12; c += 512) {
    const int row = c / 12, ch = c % 12;
    const int ggp = row / 6;
    const int rem = row % 6;
    const int t = rem >> 1, e = rem & 1;
    const int ci = ggp / 5, fi = ggp % 5;
    int plane = idp - e; if (plane > 23) plane = 23;   // odp=23,e=0: unused, clamp OOB
    int ih = ihb + t; if (ih > 47) ih = 47;            // og=23 t=2: unused, clamp
    const float* src = x + ci * XCS + (f0 + fi) * XFS + plane * XDS + ih * W_ + ch * 4;
    const f4a v = *reinterpret_cast<const f4a*>(src);
    const float v4 = (ch == 11) ? 0.f : src[4];        // x[48] slot must be 0 (n=47 pair)
    const u32 b0 = __float_as_uint(v.x), b1 = __float_as_uint(v.y);
    const u32 b2 = __float_as_uint(v.z), b3 = __float_as_uint(v.w);
    const u32 b4 = __float_as_uint(v4);
    u32* dst = lds + (4 * ch) * NRSTR + row;
    dst[0 * NRSTR] = __builtin_amdgcn_perm(b1, b0, 0x07060302u);
    dst[1 * NRSTR] = __builtin_amdgcn_perm(b2, b1, 0x07060302u);
    dst[2 * NRSTR] = __builtin_amdgcn_perm(b3, b2, 0x07060302u);
    dst[3 * NRSTR] = __builtin_amdgcn_perm(b4, b3, 0x07060302u);
  }
  __syncthreads();

  const int w = tid >> 6, lane = tid & 63;
  const int half = w >> 2;                             // 0: od=2p (pd0), 1: od=2p+1 (pd1)
  const int od = 2 * odp + half;
  if (od > 46) return;                                 // odp=23 pd1 half: no od=47
  int oh = og * 4 + (w & 3);
  if (oh > 94) oh = 93;                                // og=23,w&3=3: dup of w&3=1 (benign)
  if (half) {
    if (oh & 1) wave_body<1, 1>(lds, A, out, f0, od, oh, ihb, lane);
    else        wave_body<1, 0>(lds, A, out, f0, od, oh, ihb, lane);
  } else {
    if (oh & 1) wave_body<0, 1>(lds, A, out, f0, od, oh, ihb, lane);
    else        wave_body<0, 0>(lds, A, out, f0, od, oh, ihb, lane);
  }
}
}  // namespace

extern "C" void kernel_launch(void* const* d_in, const int* in_sizes, int n_in,
                              void* d_out, int out_size, void* d_ws, size_t ws_size,
                              hipStream_t stream) {
  const float* x = (const float*)d_in[0];
  const float* w = (const float*)d_in[1];
  float* out = (float*)d_out;
  unsigned short* A = (unsigned short*)d_ws;           // 7168 shorts = 14 KB
  hipLaunchKernelGGL(pack_kernel, dim3(8), dim3(256), 0, stream, w, A);
  hipLaunchKernelGGL(convt4d_kernel, dim3(NBLK), dim3(512), 0, stream, x, A, out);
}

// Round 28
// 30.302 us; speedup vs baseline: 1.2880x; 1.0475x over previous
//
#include <hip/hip_runtime.h>

// ConvTranspose4d via bf16 MFMA (R28 = R27 + 256-thread fine-grained blocks).
// Gather: out[co,f,od,oh,ow] = sum_{ci,i,kd,kh,kw} x[ci,f+i,id,ih,iw]*W[ci,co,i,kd,kh,kw]
// Stack: R16 E/O fold; R17 LDS staging; R19 od-pair; R22 transposed [n][row];
//   R23/R24 f-triple; R27 dl-outer acc shrink (31.7us best).
// R28: block = od-pair x 2-oh-group x f-triple, 256 thr (4 waves). LDS tile 240->160
//   rows (t-span 2) = 31.1KB -> 5 blocks/CU resident (was 3): 5 overlapping
//   stage/compute phases per CU, half-size barriers, finer tail. Theory: R27 is
//   phase-bound (issue ~5.3K cyc/block vs ~3x wall), not issue-bound; +33% staged-row
//   redundancy (160 rows/4 waves) is the accepted cost. th becomes compile-time (=PH).
//   og2=47 odd wave: oh=95 -> clamp 94, dispatches as PH0 dup of sibling (benign).
//   Per-output K-order/bits unchanged -> absmax must stay EXACTLY 0.0078125 (gate).

typedef float  f32x4  __attribute__((ext_vector_type(4)));
typedef float  f4a    __attribute__((ext_vector_type(4)));
typedef short  bf16x8 __attribute__((ext_vector_type(8)));
typedef unsigned int u32;
typedef u32    u32x2  __attribute__((ext_vector_type(2)));
typedef u32    u32x4  __attribute__((ext_vector_type(4)));

namespace {
constexpr int T_ = 8, D_ = 24, H_ = 48, W_ = 48;
constexpr int TO = 6, DO_ = 47, HO = 95, WO = 95;
constexpr int XCS = T_ * D_ * H_ * W_;
constexpr int XFS = D_ * H_ * W_;
constexpr int XDS = H_ * W_;
constexpr long OCS = (long)TO * DO_ * HO * WO;
constexpr int OFS = DO_ * HO * WO;
constexpr int ODS = HO * WO;

constexpr int AG[4] = {24, 12, 12, 8};
constexpr int AOFF[4] = {0, 3072, 4608, 6144};         // shorts; total 7168 = 14 KB
constexpr int NRSTR = 162;                             // per-column row stride (u32)

__global__ __launch_bounds__(256) void pack_kernel(const float* __restrict__ w,
                                                   unsigned short* __restrict__ A) {
  const int tid = blockIdx.x * 256 + threadIdx.x;
  const int nthr = gridDim.x * 256;
  const int KR[4] = {192, 96, 96, 48};
  for (int c = 0; c < 4; ++c) {
    const int cnt = AG[c] * 128;                       // [g][r(16)][j(8)] shorts
    for (int e = tid; e < cnt; e += nthr) {
      const int j = e & 7, r = (e >> 3) & 15, g = e >> 7;
      const int k = g * 8 + j;
      float v = 0.f;
      if (k < KR[c]) {
        int gg = -1, kd = 1, kh = 1;
        const int cc = j & 1;
        if (c == 0)      { gg = g;               kd = ((j >> 1) & 1) ? 2 : 0; kh = ((j >> 2) & 1) ? 0 : 2; }
        else if (c == 1) { gg = 2 * g + (j >> 2); kd = ((j >> 1) & 1) ? 2 : 0; kh = 1; }
        else if (c == 2) { gg = 2 * g + (j >> 2); kd = 1; kh = ((j >> 1) & 1) ? 0 : 2; }
        else             { gg = 4 * g + (j >> 1); kd = 1; kh = 1; }
        if (gg >= 0 && gg < 24) {
          const int ci = gg / 3, i = gg - 3 * (gg / 3);
          const int co = r & 7;
          int kw = (r < 8) ? (cc == 0 ? 1 : -1) : (cc == 0 ? 2 : 0);
          if (kw >= 0) v = w[ci * 648 + co * 81 + i * 27 + kd * 9 + kh * 3 + kw];
        }
      }
      u32 u = __float_as_uint(v);
      u += 0x7FFFu + ((u >> 16) & 1u);                 // RNE to bf16
      A[AOFF[c] + e] = (unsigned short)(u >> 16);
    }
  }
}

// row group base (gg = ci*3+i, dl = f-offset 0..2): gg' = ci*5 + i + dl; 4 rows/gg'
__device__ __forceinline__ int rowb(int gg, int dl) {
  const int ci = gg / 3;
  return (ci * 5 + (gg - 3 * ci) + dl) * 4;
}

template<int PD, int PH>
__device__ __forceinline__ void wave_body(
    const u32* __restrict__ lds, const unsigned short* __restrict__ A,
    float* __restrict__ out, int f0, int od, int oh, int lane)
{
  constexpr int CLS = (PD && PH) ? 0 : PD ? 1 : PH ? 2 : 3;
  constexpr int NSTEP = (CLS == 0) ? 6 : (CLS == 3) ? 2 : 3;
  constexpr int TH = PH;                               // compile-time top h-row
  const int c15 = lane & 15, q = lane >> 4;

  bf16x8 af[NSTEP];
  {
    const unsigned short* Ap = A + AOFF[CLS] + c15 * 8;
    #pragma unroll
    for (int s = 0; s < NSTEP; ++s)
      af[s] = *reinterpret_cast<const bf16x8*>(Ap + (s * 4 + q) * 128);
  }

  const int isO = (q >= 2);
  const int co0 = (q & 1) * 4;

  #pragma unroll
  for (int dl = 0; dl < 3; ++dl) {                     // dl OUTER (R27)
    f32x4 acc[3];
    #pragma unroll
    for (int b = 0; b < 3; ++b) acc[b] = {0, 0, 0, 0};

    #pragma unroll
    for (int blk = 0; blk < 3; ++blk) {
      const int n = blk * 16 + c15;
      const u32* col = lds + n * NRSTR;
      #pragma unroll
      for (int s = 0; s < NSTEP; ++s) {
        const int G = s * 4 + q;
        u32x4 ue;
        if constexpr (CLS == 0) {                      // rows rowb + {0,1,2,3} (TH=1)
          const u32* b = col + rowb(G, dl) + 2 * TH - 2;
          const u32x2 lo = *reinterpret_cast<const u32x2*>(b);
          const u32x2 hi = *reinterpret_cast<const u32x2*>(b + 2);
          ue = u32x4{lo.x, lo.y, hi.x, hi.y};
        } else if constexpr (CLS == 1) {               // (g0,e0),(g0,e1),(g1,e0),(g1,e1)
          const u32* b0 = col + rowb(2 * G, dl) + 2 * TH;
          const u32* b1 = col + rowb(2 * G + 1, dl) + 2 * TH;
          const u32x2 lo = *reinterpret_cast<const u32x2*>(b0);
          const u32x2 hi = *reinterpret_cast<const u32x2*>(b1);
          ue = u32x4{lo.x, lo.y, hi.x, hi.y};
        } else if constexpr (CLS == 2) {               // (g,TH-1),(g,TH) e=1 pairs
          const int r0 = rowb(2 * G, dl), r1 = rowb(2 * G + 1, dl);
          ue = u32x4{col[r0 + 2 * TH - 1], col[r0 + 2 * TH + 1],
                     col[r1 + 2 * TH - 1], col[r1 + 2 * TH + 1]};
        } else {                                       // g ascending, e=1, t=TH
          #pragma unroll
          for (int d = 0; d < 4; ++d) {
            int gg = 4 * G + d; gg = (gg > 23) ? 23 : gg;  // k>=48 -> A==0, row dontcare
            ue[d] = col[rowb(gg, dl) + 2 * TH + 1];
          }
        }
        acc[blk] = __builtin_amdgcn_mfma_f32_16x16x32_bf16(af[s], __builtin_bit_cast(bf16x8, ue), acc[blk], 0, 0, 0);
      }
    }

    // store frame f0+dl: D rows 0-7 = co (even ow), 8-15 = co (odd ow)
    #pragma unroll
    for (int blk = 0; blk < 3; ++blk) {
      const int ow = blk * 32 + 2 * c15 + isO;
      if (ow < 95) {
        const long ob = (long)(f0 + dl) * OFS + (long)od * ODS + (long)oh * HO + ow;
        #pragma unroll
        for (int j = 0; j < 4; ++j)
          out[(long)(co0 + j) * OCS + ob] = acc[blk][j];
      }
    }
  }
}

constexpr int NBLK = 2 * 24 * 48;                      // f-triple x od-pair x og2 = 2304

__global__ __launch_bounds__(256) void convt4d_kernel(
    const float* __restrict__ x, const unsigned short* __restrict__ A,
    float* __restrict__ out)
{
  __shared__ u32 lds[48 * NRSTR];                      // 31104 B

  constexpr int qq = NBLK / 8;                         // 288 (NBLK%8==0)
  const int bid = blockIdx.x;
  const int L = (bid & 7) * qq + (bid >> 3);           // bijective XCD swizzle
  const int og2 = L % 48;                              // oh pair {2*og2, 2*og2+1}
  const int rest = L / 48;
  const int odp = rest % 24, fp = rest / 24;           // od pair {2odp,2odp+1}; f-triple
  const int f0 = 3 * fp;                               // f0 in {0,3}; frames f0..f0+4

  const int tid = threadIdx.x;
  const int idp = odp + 1;                             // e=0 plane = p+1, e=1 plane = p

  // stage 160-row union PRE-PACKED + TRANSPOSED: lds[n*NRSTR + row] =
  //   bf(x[n]) | bf(x[n+1])<<16 ; row = (ci*5 + fi)*4 + t*2 + e, t in {0,1}
  for (int row = tid; row < 160; row += 256) {
    const int ggp = row >> 2;
    const int rem = row & 3;
    const int t = rem >> 1, e = rem & 1;
    const int ci = ggp / 5, fi = ggp % 5;
    int plane = idp - e; if (plane > 23) plane = 23;   // odp=23,e=0: unused, clamp OOB
    int ih = og2 + t; if (ih > 47) ih = 47;            // og2=47,t=1: unused, clamp
    const float* src = x + ci * XCS + (f0 + fi) * XFS + plane * XDS + ih * W_;
    f32x4 v[12];
    #pragma unroll
    for (int ch = 0; ch < 12; ++ch)
      v[ch] = *reinterpret_cast<const f4a*>(src + ch * 4);
    u32* dst = lds + row;
    #pragma unroll
    for (int ch = 0; ch < 12; ++ch) {
      const u32 b0 = __float_as_uint(v[ch].x), b1 = __float_as_uint(v[ch].y);
      const u32 b2 = __float_as_uint(v[ch].z), b3 = __float_as_uint(v[ch].w);
      const u32 b4 = (ch == 11) ? 0u : __float_as_uint(v[ch + 1].x);
      dst[(4 * ch + 0) * NRSTR] = __builtin_amdgcn_perm(b1, b0, 0x07060302u);
      dst[(4 * ch + 1) * NRSTR] = __builtin_amdgcn_perm(b2, b1, 0x07060302u);
      dst[(4 * ch + 2) * NRSTR] = __builtin_amdgcn_perm(b3, b2, 0x07060302u);
      dst[(4 * ch + 3) * NRSTR] = __builtin_amdgcn_perm(b4, b3, 0x07060302u);
    }
  }
  __syncthreads();

  const int w = tid >> 6, lane = tid & 63;
  const int half = w >> 1;                             // 0: od=2p (pd0), 1: od=2p+1 (pd1)
  const int od = 2 * odp + half;
  if (od > 46) return;                                 // odp=23 pd1 half: no od=47
  int oh = og2 * 2 + (w & 1);
  if (oh > 94) oh = 94;                                // og2=47 odd wave: dup of even (benign)
  if (half) {
    if (oh & 1) wave_body<1, 1>(lds, A, out, f0, od, oh, lane);
    else        wave_body<1, 0>(lds, A, out, f0, od, oh, lane);
  } else {
    if (oh & 1) wave_body<0, 1>(lds, A, out, f0, od, oh, lane);
    else        wave_body<0, 0>(lds, A, out, f0, od, oh, lane);
  }
}
}  // namespace

extern "C" void kernel_launch(void* const* d_in, const int* in_sizes, int n_in,
                              void* d_out, int out_size, void* d_ws, size_t ws_size,
                              hipStream_t stream) {
  const float* x = (const float*)d_in[0];
  const float* w = (const float*)d_in[1];
  float* out = (float*)d_out;
  unsigned short* A = (unsigned short*)d_ws;           // 7168 shorts = 14 KB
  hipLaunchKernelGGL(pack_kernel, dim3(8), dim3(256), 0, stream, w, A);
  hipLaunchKernelGGL(convt4d_kernel, dim3(NBLK), dim3(256), 0, stream, x, A, out);
}